// Round 1
// 5279.359 us; speedup vs baseline: 1.4722x; 1.4722x over previous
//
#include <hip/hip_runtime.h>
#include <hip/hip_bf16.h>

typedef __attribute__((ext_vector_type(8))) short short8;
typedef __attribute__((ext_vector_type(4))) float floatx4;
typedef __attribute__((ext_vector_type(4))) int intx4;

#define T_STEPS 512
#define BATCH   32
#define HDIM    1024
#define GATE4   4096
#define DA_DIM  64
#define PWG     128
#define RING    16
#define AROWS   8
#define EPS_LN  1e-5f

// round-to-nearest-even fp32 -> bf16 bit pattern. Finite input can never
// produce 0xFFFF, so 0xFFFFFFFF dwords are a safe "not yet written" sentinel.
__device__ __forceinline__ unsigned short f2bf(float f) {
    unsigned u = __float_as_uint(f);
    unsigned r = (u + 0x7FFFu + ((u >> 16) & 1u)) >> 16;
    return (unsigned short)r;
}

// device-coherent 16B ops (to coherence point / IF$)
__device__ __forceinline__ void coh_store16(void* p, intx4 v) {
    asm volatile("global_store_dwordx4 %0, %1, off sc0 sc1" :: "v"(p), "v"(v) : "memory");
}
__device__ __forceinline__ short8 coh_load16(const void* p) {
    short8 v;
    asm volatile("global_load_dwordx4 %0, %1, off sc0 sc1" : "=v"(v) : "v"(p) : "memory");
    return v;
}
__device__ __forceinline__ void waitcnt_vm0() {
    asm volatile("s_waitcnt vmcnt(0)" ::: "memory");
}

// ---------------------------------------------------------------------------
// W fragment prep: wf[w][mt][kb][lane][j]  (A-operand layout, K=[x;h], 2048)
// ---------------------------------------------------------------------------
__global__ void __launch_bounds__(256) prep_wfrag(
    const float* __restrict__ Wih, const float* __restrict__ Whh,
    unsigned short* __restrict__ wf)
{
    int gid  = blockIdx.x * 256 + threadIdx.x;   // 1,048,576
    int lane = gid & 63;
    int kb   = (gid >> 6) & 63;
    int mt   = (gid >> 12) & 1;
    int w    = gid >> 13;                        // 0..127
    int m    = lane & 15;
    int row  = (m >> 2) * HDIM + w * 8 + mt * 4 + (m & 3);
    int k0   = kb * 32 + (lane >> 4) * 8;
    const float* src = (k0 < HDIM) ? (Wih + (size_t)row * HDIM + k0)
                                   : (Whh + (size_t)row * HDIM + (k0 - HDIM));
    unsigned short* dst = wf + (size_t)gid * 8;
#pragma unroll
    for (int j = 0; j < 8; ++j) dst[j] = f2bf(src[j]);
}

// ---------------------------------------------------------------------------
// x fragment prep: per t, xf[t][kb][nb][lane][j]  (B-operand layout)
// ---------------------------------------------------------------------------
__global__ void __launch_bounds__(256) prep_xfrag(
    const float* __restrict__ x, unsigned short* __restrict__ xf)
{
    int gid  = blockIdx.x * 256 + threadIdx.x;   // 2,097,152
    int lane = gid & 63;
    int nb   = (gid >> 6) & 1;
    int kb   = (gid >> 7) & 31;
    int t    = gid >> 12;
    int b    = nb * 16 + (lane & 15);
    int k0   = kb * 32 + (lane >> 4) * 8;
    const float* src = x + ((size_t)(t * BATCH + b)) * HDIM + k0;
    unsigned short* dst = xf + (size_t)t * 32768 + (((kb * 2 + nb) * 64 + lane) * 8);
#pragma unroll
    for (int j = 0; j < 8; ++j) dst[j] = f2bf(src[j]);
}

// ---------------------------------------------------------------------------
// Persistent LSTM layer: 128 WGs x 256 thr (1 WG/CU). WG w owns h-dims
// [w*8,w*8+8) = 32 gate rows. Weights LDS-resident (128 KB, staged once).
//
// Sync: SENTINEL-IN-DATA. Ring slots are pre-filled with 0xFF; producers
// publish h as 16B coherent stores (no drain, no flag); each wave polls its
// own 16 KB K-chunk with coherent dwordx4 loads until no dword == -1. The
// successful poll attempt IS the data load (one coherent round trip/step).
// Slot reuse: at step t, after all 4 waves' polls of h(t-1) pass (== proof
// that every WG finished consuming h(t-2)), WG w re-sentinels its own 512 B
// region of h(t-2)'s slot. Reuse distance RING=16 >> skew bound (<1 step).
// ---------------------------------------------------------------------------
__global__ void __launch_bounds__(256, 1) lstm_persistent(
    const unsigned short* __restrict__ xf,
    const unsigned short* __restrict__ wf,
    unsigned short* __restrict__ ring,
    const float* __restrict__ bih, const float* __restrict__ bhh,
    float* __restrict__ cbuf,
    float* __restrict__ hs,
    int slot0)
{
    __shared__ short8 wlds[8192];         // 128 KB: [mt*64 + (isH*32+kb)][lane]
    __shared__ float part[16 * 256];      // 16 KB
    __shared__ float gates[2 * 16 * 32];  // 4 KB
    __shared__ float bias_s[32];
    __shared__ intx4 hstage4[32];

    const int tid  = threadIdx.x;
    const int w    = blockIdx.x;
    const int lane = tid & 63;
    const int v    = tid >> 6;

    // ---- stage weights global -> LDS (once per layer) ----
    {
        const short8* wsrc = (const short8*)(wf + (size_t)w * 65536);
        for (int i = tid; i < 8192; i += 256) wlds[i] = wsrc[i];
    }
    if (tid < 32) {
        int mt = tid >> 4, m = tid & 15;
        int row = (m >> 2) * HDIM + w * 8 + mt * 4 + (m & 3);
        bias_s[tid] = bih[row] + bhh[row];
    }
    const int hd = tid >> 5;          // 0..7 local h-dim
    const int bb = tid & 31;          // batch
    const int j  = w * 8 + hd;        // global h-dim
    float creg = cbuf[bb * HDIM + j];
    __syncthreads();

    int slot = slot0;
    for (int t = 0; t < T_STEPS; ++t) {
        const unsigned short* xb = xf + (size_t)t * 32768;

        // x loads (global; L2-amortized per XCD)
        short8 xv[8][2];
#pragma unroll
        for (int i = 0; i < 8; ++i) {
            const unsigned short* xp = xb + (size_t)((v * 8 + i) * 128 + lane) * 8;
            xv[i][0] = *(const short8*)xp;
            xv[i][1] = *(const short8*)(xp + 512);
        }

        floatx4 a00 = {0.f,0.f,0.f,0.f}, a01 = {0.f,0.f,0.f,0.f};
        floatx4 a10 = {0.f,0.f,0.f,0.f}, a11 = {0.f,0.f,0.f,0.f};

        // ---- x-part MFMAs (A from LDS) — overlaps other WGs' publish ----
#pragma unroll
        for (int i = 0; i < 8; ++i) {
            int kb = v * 8 + i;
            short8 wa0 = wlds[(0 * 64 + kb) * 64 + lane];
            short8 wa1 = wlds[(1 * 64 + kb) * 64 + lane];
            a00 = __builtin_amdgcn_mfma_f32_16x16x32_bf16(wa0, xv[i][0], a00, 0, 0, 0);
            a01 = __builtin_amdgcn_mfma_f32_16x16x32_bf16(wa0, xv[i][1], a01, 0, 0, 0);
            a10 = __builtin_amdgcn_mfma_f32_16x16x32_bf16(wa1, xv[i][0], a10, 0, 0, 0);
            a11 = __builtin_amdgcn_mfma_f32_16x16x32_bf16(wa1, xv[i][1], a11, 0, 0, 0);
        }

        // ---- h(t-1): per-wave sentinel poll on own 16 KB K-chunk.
        //      The attempt that passes IS the data load. ----
        const unsigned short* rb = ring + (size_t)slot * 32768;
        short8 hv[8][2];
        {
            const unsigned short* hp0 = rb + (size_t)(v * 8 * 128 + lane) * 8;
            for (;;) {
#pragma unroll
                for (int i = 0; i < 8; ++i) {
                    const unsigned short* hp = hp0 + (size_t)i * 1024;
                    hv[i][0] = coh_load16(hp);
                    hv[i][1] = coh_load16(hp + 512);
                }
                waitcnt_vm0();
                int ok = 1;
#pragma unroll
                for (int i = 0; i < 8; ++i)
#pragma unroll
                    for (int u = 0; u < 2; ++u) {
                        intx4 q = __builtin_bit_cast(intx4, hv[i][u]);
                        ok &= (q.x != -1) & (q.y != -1) & (q.z != -1) & (q.w != -1);
                    }
                if (__all(ok)) break;
                __builtin_amdgcn_s_sleep(1);
            }
        }

        // ---- h-part MFMAs ----
#pragma unroll
        for (int i = 0; i < 8; ++i) {
            int kh = v * 8 + i;
            short8 wa0 = wlds[(0 * 64 + 32 + kh) * 64 + lane];
            short8 wa1 = wlds[(1 * 64 + 32 + kh) * 64 + lane];
            a00 = __builtin_amdgcn_mfma_f32_16x16x32_bf16(wa0, hv[i][0], a00, 0, 0, 0);
            a01 = __builtin_amdgcn_mfma_f32_16x16x32_bf16(wa0, hv[i][1], a01, 0, 0, 0);
            a10 = __builtin_amdgcn_mfma_f32_16x16x32_bf16(wa1, hv[i][0], a10, 0, 0, 0);
            a11 = __builtin_amdgcn_mfma_f32_16x16x32_bf16(wa1, hv[i][1], a11, 0, 0, 0);
        }

        // ---- cross-wave K reduction via LDS ----
        {
            int n = lane & 15, q = lane >> 4;
#pragma unroll
            for (int r = 0; r < 4; ++r) {
                int m16 = (q * 4 + r) * 16 + n;
                part[(v * 4 + 0) * 256 + m16] = a00[r];
                part[(v * 4 + 1) * 256 + m16] = a01[r];
                part[(v * 4 + 2) * 256 + m16] = a10[r];
                part[(v * 4 + 3) * 256 + m16] = a11[r];
            }
        }
        __syncthreads();
        // ---- retire slot of h(t-2): all 4 waves passed their polls of
        //      h(t-1) ==> every WG published h(t-1) ==> every WG is done
        //      re-reading h(t-2). Re-sentinel our own 512 B region. ----
        if (tid < 32) {
            unsigned short* sp = ring + (size_t)((slot + RING - 1) & (RING - 1)) * 32768;
            int kb2   = w >> 2;
            int lane2 = ((w & 3) << 4) | (tid & 15);
            intx4 ff = {-1, -1, -1, -1};
            coh_store16(sp + (size_t)((kb2 * 2 + (tid >> 4)) * 64 + lane2) * 8, ff);
        }
        {
            int m = tid >> 4, n = tid & 15;
            int m16 = m * 16 + n;
#pragma unroll
            for (int mt = 0; mt < 2; ++mt)
#pragma unroll
                for (int nb = 0; nb < 2; ++nb) {
                    int c = mt * 2 + nb;
                    float g = part[(0 * 4 + c) * 256 + m16]
                            + part[(1 * 4 + c) * 256 + m16]
                            + part[(2 * 4 + c) * 256 + m16]
                            + part[(3 * 4 + c) * 256 + m16];
                    gates[(mt * 16 + m) * 32 + nb * 16 + n] = g + bias_s[mt * 16 + m];
                }
        }
        __syncthreads();

        // ---- gate nonlinearities + c/h update (one (hd,bb) per thread) ----
        float hval;
        {
            int r3 = hd & 3, mt = hd >> 2;
            float gi = gates[(mt * 16 +  0 + r3) * 32 + bb];
            float gf = gates[(mt * 16 +  4 + r3) * 32 + bb];
            float gg = gates[(mt * 16 +  8 + r3) * 32 + bb];
            float go = gates[(mt * 16 + 12 + r3) * 32 + bb];
            float i_ = 1.f / (1.f + __expf(-gi));
            float f_ = 1.f / (1.f + __expf(-gf));
            float g_ = tanhf(gg);
            float o_ = 1.f / (1.f + __expf(-go));
            creg = f_ * creg + i_ * g_;
            hval = o_ * tanhf(creg);
            ((unsigned short*)&hstage4[bb])[hd] = f2bf(hval);
        }
        __syncthreads();

        // ---- publish h(t): 32x16B coherent stores. No drain, no flag —
        //      consumers detect arrival via the sentinel check. ----
        int slot_out = (slot + 1) & (RING - 1);
        if (tid < 32) {
            unsigned short* hn = ring + (size_t)slot_out * 32768;
            int kb2   = w >> 2;
            int lane2 = ((w & 3) << 4) | (tid & 15);
            coh_store16(hn + (size_t)((kb2 * 2 + (tid >> 4)) * 64 + lane2) * 8,
                        hstage4[tid]);
        }
        // hs history store (not on the critical path)
        hs[((size_t)t * BATCH + bb) * HDIM + j] = hval;
        slot = slot_out;
    }
    cbuf[bb * HDIM + j] = creg;
}

// ---------------------------------------------------------------------------
// Adapter (x + up(relu(down(x)))) + LayerNorm. 8 rows per WG (2048 WGs):
// Adw/Auw streamed once per WG (L2 traffic /8), full-K per-thread dots.
// ---------------------------------------------------------------------------
__global__ void __launch_bounds__(256) adapter_ln(
    const float* __restrict__ xin,
    const float* __restrict__ Adw, const float* __restrict__ Adb,
    const float* __restrict__ Auw, const float* __restrict__ Aub,
    const float* __restrict__ lng, const float* __restrict__ lnb,
    float* __restrict__ outf, unsigned short* __restrict__ xfout)
{
    __shared__ float xs[AROWS * 1024];     // 32 KB
    __shared__ float dbuf[AROWS * 64];     // 2 KB
    __shared__ float red2[AROWS * 32 * 2]; // 2 KB
    __shared__ float mv[AROWS * 2];
    const int tid = threadIdx.x;
    const int r0  = blockIdx.x * AROWS;

    // stage 8 rows (coalesced float4)
    {
        const float4* src4 = (const float4*)(xin + (size_t)r0 * HDIM);
        float4* xs4 = (float4*)xs;
        for (int i = tid; i < AROWS * 256; i += 256) xs4[i] = src4[i];
    }
    __syncthreads();

    const int row = tid >> 5;   // 0..7
    const int sg  = tid & 31;

    // ---- down-proj: thread computes d[row][2 a's] over full K ----
    {
        const float4* w0 = (const float4*)Adw + (size_t)(sg * 2) * 256;
        const float4* w1 = w0 + 256;
        const float4* xr = (const float4*)xs + row * 256;
        float acc0 = 0.f, acc1 = 0.f;
#pragma unroll 4
        for (int k = 0; k < 256; ++k) {
            float4 xv = xr[k];
            float4 wa = w0[k], wb = w1[k];
            acc0 += wa.x*xv.x + wa.y*xv.y + wa.z*xv.z + wa.w*xv.w;
            acc1 += wb.x*xv.x + wb.y*xv.y + wb.z*xv.z + wb.w*xv.w;
        }
        acc0 += Adb[sg * 2];
        acc1 += Adb[sg * 2 + 1];
        dbuf[row * 64 + sg * 2]     = acc0 > 0.f ? acc0 : 0.f;
        dbuf[row * 64 + sg * 2 + 1] = acc1 > 0.f ? acc1 : 0.f;
    }
    __syncthreads();

    // ---- up-proj: thread owns 32 consecutive j for its row ----
    float4 dr[16];
    {
        const float4* dv = (const float4*)(dbuf + row * 64);
#pragma unroll
        for (int q = 0; q < 16; ++q) dr[q] = dv[q];
    }
    float y[32]; float s1 = 0.f, s2 = 0.f;
#pragma unroll 4
    for (int jj = 0; jj < 32; ++jj) {
        int jidx = sg * 32 + jj;
        const float4* urow = (const float4*)(Auw + (size_t)jidx * DA_DIM);
        float acc = xs[row * 1024 + jidx] + Aub[jidx];
#pragma unroll
        for (int q = 0; q < 16; ++q) {
            float4 uv = urow[q];
            acc += uv.x*dr[q].x + uv.y*dr[q].y + uv.z*dr[q].z + uv.w*dr[q].w;
        }
        y[jj] = acc; s1 += acc; s2 += acc * acc;
    }
    red2[(row * 32 + sg) * 2]     = s1;
    red2[(row * 32 + sg) * 2 + 1] = s2;
    __syncthreads();
    if (sg == 0) {
        float t1 = 0.f, t2 = 0.f;
        for (int q = 0; q < 32; ++q) {
            t1 += red2[(row * 32 + q) * 2];
            t2 += red2[(row * 32 + q) * 2 + 1];
        }
        float mean = t1 * (1.f / 1024.f);
        float var  = t2 * (1.f / 1024.f) - mean * mean;
        mv[row * 2]     = mean;
        mv[row * 2 + 1] = rsqrtf(var + EPS_LN);
    }
    __syncthreads();
    const float mean = mv[row * 2], rstd = mv[row * 2 + 1];
    const int rg = r0 + row;
    // normalize
#pragma unroll
    for (int jj = 0; jj < 32; ++jj) {
        int jidx = sg * 32 + jj;
        y[jj] = (y[jj] - mean) * rstd * lng[jidx] + lnb[jidx];
    }
    if (outf) {
        float4* o4 = (float4*)(outf + (size_t)rg * HDIM + sg * 32);
#pragma unroll
        for (int q = 0; q < 8; ++q) {
            float4 ov = { y[q*4], y[q*4+1], y[q*4+2], y[q*4+3] };
            o4[q] = ov;
        }
    }
    if (xfout) {
        int t = rg >> 5, b = rg & 31;
        int nb = b >> 4;
        unsigned short* base = xfout + (size_t)t * 32768;
#pragma unroll
        for (int g = 0; g < 4; ++g) {
            int lane2 = (g << 4) | (b & 15);
            unsigned short tmp[8];
#pragma unroll
            for (int e = 0; e < 8; ++e) tmp[e] = f2bf(y[g * 8 + e]);
            *(short8*)(base + (size_t)((sg * 2 + nb) * 64 + lane2) * 8) = *(short8*)tmp;
        }
    }
}

extern "C" void kernel_launch(void* const* d_in, const int* in_sizes, int n_in,
                              void* d_out, int out_size, void* d_ws, size_t ws_size,
                              hipStream_t stream)
{
    const float* x   = (const float*)d_in[0];
    const float* Wih = (const float*)d_in[1];
    const float* Whh = (const float*)d_in[2];
    const float* bih = (const float*)d_in[3];
    const float* bhh = (const float*)d_in[4];
    const float* Adw = (const float*)d_in[5];
    const float* Adb = (const float*)d_in[6];
    const float* Auw = (const float*)d_in[7];
    const float* Aub = (const float*)d_in[8];
    const float* lng = (const float*)d_in[9];
    const float* lnb = (const float*)d_in[10];
    float* out = (float*)d_out;

    // workspace carve (~52 MB)
    char* ws = (char*)d_ws;
    unsigned short* wfb  = (unsigned short*)ws; ws += (size_t)GATE4 * 2048 * 2;      // 16.78 MB
    unsigned short* xfb  = (unsigned short*)ws; ws += (size_t)T_STEPS * 32768 * 2;   // 33.55 MB
    unsigned short* ring = (unsigned short*)ws; ws += (size_t)RING * 32768 * 2;      // 1 MB
    float*    cbuf  = (float*)ws;    ws += (size_t)BATCH * HDIM * 4;                 // 128 KB
    float* hs = out;   // alias hs onto d_out x-region (adapter is in-place safe)

    hipMemsetAsync(cbuf, 0, (size_t)BATCH * HDIM * 4, stream);
    // slot 0 = h0 = zeros (valid data); slots 1..15 = 0xFF sentinel
    hipMemsetAsync(ring, 0, 65536, stream);
    hipMemsetAsync((char*)ring + 65536, 0xFF, (size_t)(RING - 1) * 65536, stream);

    prep_xfrag<<<8192, 256, 0, stream>>>(x, xfb);

    for (int l = 0; l < 2; ++l) {
        prep_wfrag<<<4096, 256, 0, stream>>>(Wih + (size_t)l * GATE4 * HDIM,
                                             Whh + (size_t)l * GATE4 * HDIM, wfb);
        // global step g = l*512 + t; slot_in = g & 15; 512 % 16 == 0 so slot0 = 0
        // for both layers and the sentinel protocol is continuous across layers.
        lstm_persistent<<<PWG, 256, 0, stream>>>(xfb, wfb, ring,
                                                 bih + (size_t)l * GATE4,
                                                 bhh + (size_t)l * GATE4,
                                                 cbuf, hs, 0);

        const float* adw = Adw + (size_t)l * DA_DIM * HDIM;
        const float* adb = Adb + (size_t)l * DA_DIM;
        const float* auw = Auw + (size_t)l * HDIM * DA_DIM;
        const float* aub = Aub + (size_t)l * HDIM;
        const float* lg  = lng + (size_t)l * HDIM;
        const float* lb  = lnb + (size_t)l * HDIM;
        if (l == 0) {
            adapter_ln<<<T_STEPS * BATCH / AROWS, 256, 0, stream>>>(
                hs, adw, adb, auw, aub, lg, lb, nullptr, xfb);
        } else {
            hipMemcpyAsync(out + 16777216, hs + (size_t)511 * BATCH * HDIM,
                           (size_t)BATCH * HDIM * 4, hipMemcpyDeviceToDevice, stream);
            hipMemcpyAsync(out + 16777216 + 32768, cbuf,
                           (size_t)BATCH * HDIM * 4, hipMemcpyDeviceToDevice, stream);
            adapter_ln<<<T_STEPS * BATCH / AROWS, 256, 0, stream>>>(
                hs, adw, adb, auw, aub, lg, lb, out, nullptr);
        }
    }
}

// Round 2
// 5043.778 us; speedup vs baseline: 1.5409x; 1.0467x over previous
//
#include <hip/hip_runtime.h>
#include <hip/hip_bf16.h>

typedef __attribute__((ext_vector_type(8))) short short8;
typedef __attribute__((ext_vector_type(4))) float floatx4;
typedef __attribute__((ext_vector_type(4))) int intx4;

#define T_STEPS 512
#define BATCH   32
#define HDIM    1024
#define GATE4   4096
#define DA_DIM  64
#define PWG     128
#define RING    16
#define AROWS   8
#define EPS_LN  1e-5f

// LDS bank-conflict swizzles: flip addr bit4 with row-(quad)parity so a
// wave's 64 lanes reach all 32 banks (2-way max) instead of 16 (4-way).
#define PSWZ(row, n) ((((row) * 16 + (n))) ^ ((((row) >> 2) & 1) << 4))
#define GSWZ(row, col) ((row) * 32 + (((col) ^ (((row) & 1) << 4))))

// round-to-nearest-even fp32 -> bf16 bit pattern. Finite input can never
// produce 0xFFFF, so 0xFFFFFFFF dwords are a safe "not yet written" sentinel.
__device__ __forceinline__ unsigned short f2bf(float f) {
    unsigned u = __float_as_uint(f);
    unsigned r = (u + 0x7FFFu + ((u >> 16) & 1u)) >> 16;
    return (unsigned short)r;
}

__device__ __forceinline__ float fast_sigmoid(float x) {
    return __builtin_amdgcn_rcpf(1.f + __expf(-x));
}
__device__ __forceinline__ float fast_tanh(float x) {
    // tanh(x) = 1 - 2/(1+exp(2x)); saturates correctly at +/-inf
    return 1.f - 2.f * __builtin_amdgcn_rcpf(1.f + __expf(2.f * x));
}

// device-coherent 16B ops (to coherence point / IF$)
__device__ __forceinline__ void coh_store16(void* p, intx4 v) {
    asm volatile("global_store_dwordx4 %0, %1, off sc0 sc1" :: "v"(p), "v"(v) : "memory");
}
__device__ __forceinline__ short8 coh_load16(const void* p) {
    short8 v;
    asm volatile("global_load_dwordx4 %0, %1, off sc0 sc1" : "=v"(v) : "v"(p) : "memory");
    return v;
}
__device__ __forceinline__ void waitcnt_vm0() {
    asm volatile("s_waitcnt vmcnt(0)" ::: "memory");
}

// ---------------------------------------------------------------------------
// W fragment prep: wf[w][mt][kb][lane][j]  (A-operand layout, K=[x;h], 2048)
// ---------------------------------------------------------------------------
__global__ void __launch_bounds__(256) prep_wfrag(
    const float* __restrict__ Wih, const float* __restrict__ Whh,
    unsigned short* __restrict__ wf)
{
    int gid  = blockIdx.x * 256 + threadIdx.x;   // 1,048,576
    int lane = gid & 63;
    int kb   = (gid >> 6) & 63;
    int mt   = (gid >> 12) & 1;
    int w    = gid >> 13;                        // 0..127
    int m    = lane & 15;
    int row  = (m >> 2) * HDIM + w * 8 + mt * 4 + (m & 3);
    int k0   = kb * 32 + (lane >> 4) * 8;
    const float* src = (k0 < HDIM) ? (Wih + (size_t)row * HDIM + k0)
                                   : (Whh + (size_t)row * HDIM + (k0 - HDIM));
    unsigned short* dst = wf + (size_t)gid * 8;
#pragma unroll
    for (int j = 0; j < 8; ++j) dst[j] = f2bf(src[j]);
}

// ---------------------------------------------------------------------------
// x fragment prep: per t, xf[t][kb][nb][lane][j]  (B-operand layout)
// ---------------------------------------------------------------------------
__global__ void __launch_bounds__(256) prep_xfrag(
    const float* __restrict__ x, unsigned short* __restrict__ xf)
{
    int gid  = blockIdx.x * 256 + threadIdx.x;   // 2,097,152
    int lane = gid & 63;
    int nb   = (gid >> 6) & 1;
    int kb   = (gid >> 7) & 31;
    int t    = gid >> 12;
    int b    = nb * 16 + (lane & 15);
    int k0   = kb * 32 + (lane >> 4) * 8;
    const float* src = x + ((size_t)(t * BATCH + b)) * HDIM + k0;
    unsigned short* dst = xf + (size_t)t * 32768 + (((kb * 2 + nb) * 64 + lane) * 8);
#pragma unroll
    for (int j = 0; j < 8; ++j) dst[j] = f2bf(src[j]);
}

// ---------------------------------------------------------------------------
// Persistent LSTM layer: 128 WGs x 256 thr (1 WG/CU = 1 wave/SIMD). WG w owns
// h-dims [w*8,w*8+8) = 32 gate rows. WEIGHTS REGISTER-RESIDENT: at 1
// wave/SIMD the full 512-VGPR budget is available; each wave's 32 weight
// fragments (128 VGPRs) are loop-invariant, so the per-step 128 KB/WG LDS
// weight stream (~1540 cy/step at 85 B/cy) is deleted and h-MFMAs become a
// pure register chain right after the poll.
//
// Sync: SENTINEL-IN-DATA (unchanged from prev round): producers publish h as
// 16B coherent stores; consumers poll their own K-chunk with coherent loads
// until no dword == -1; the passing attempt IS the data load. Slot-reuse by
// re-sentineling h(t-2)'s own region after the h(t-1) poll passes (proof all
// WGs consumed h(t-2)).  RING=16 >> skew bound (<1 step).
// ---------------------------------------------------------------------------
__global__ void __launch_bounds__(256, 1) lstm_persistent(
    const unsigned short* __restrict__ xf,
    const unsigned short* __restrict__ wf,
    unsigned short* __restrict__ ring,
    const float* __restrict__ bih, const float* __restrict__ bhh,
    float* __restrict__ cbuf,
    float* __restrict__ hs,
    int slot0)
{
    __shared__ float part[16 * 256];      // 16 KB (PSWZ-swizzled rows)
    __shared__ float gates[2 * 16 * 32];  // 4 KB (GSWZ-swizzled cols)
    __shared__ float bias_s[32];
    __shared__ intx4 hstage4[32];

    const int tid  = threadIdx.x;
    const int w    = blockIdx.x;
    const int lane = tid & 63;
    const int v    = tid >> 6;

    // ---- stage weights global -> REGISTERS (once per layer) ----
    short8 wx0[8], wx1[8], wh0[8], wh1[8];
    {
        const short8* wsrc = (const short8*)(wf + (size_t)w * 65536);
#pragma unroll
        for (int i = 0; i < 8; ++i) {
            int kb = v * 8 + i;
            wx0[i] = wsrc[(0 * 64 +      kb) * 64 + lane];
            wx1[i] = wsrc[(1 * 64 +      kb) * 64 + lane];
            wh0[i] = wsrc[(0 * 64 + 32 + kb) * 64 + lane];
            wh1[i] = wsrc[(1 * 64 + 32 + kb) * 64 + lane];
        }
    }
    if (tid < 32) {
        int mt = tid >> 4, m = tid & 15;
        int row = (m >> 2) * HDIM + w * 8 + mt * 4 + (m & 3);
        bias_s[tid] = bih[row] + bhh[row];
    }
    const int hd = tid >> 5;          // 0..7 local h-dim
    const int bb = tid & 31;          // batch
    const int j  = w * 8 + hd;        // global h-dim
    float creg = cbuf[bb * HDIM + j];
    __syncthreads();

    int slot = slot0;
    for (int t = 0; t < T_STEPS; ++t) {
        const unsigned short* xb = xf + (size_t)t * 32768;

        // x loads (global; L2-amortized per XCD)
        short8 xv[8][2];
#pragma unroll
        for (int i = 0; i < 8; ++i) {
            const unsigned short* xp = xb + (size_t)((v * 8 + i) * 128 + lane) * 8;
            xv[i][0] = *(const short8*)xp;
            xv[i][1] = *(const short8*)(xp + 512);
        }

        floatx4 a00 = {0.f,0.f,0.f,0.f}, a01 = {0.f,0.f,0.f,0.f};
        floatx4 a10 = {0.f,0.f,0.f,0.f}, a11 = {0.f,0.f,0.f,0.f};

        // ---- x-part MFMAs (all-register) — overlaps other WGs' publish ----
#pragma unroll
        for (int i = 0; i < 8; ++i) {
            a00 = __builtin_amdgcn_mfma_f32_16x16x32_bf16(wx0[i], xv[i][0], a00, 0, 0, 0);
            a01 = __builtin_amdgcn_mfma_f32_16x16x32_bf16(wx0[i], xv[i][1], a01, 0, 0, 0);
            a10 = __builtin_amdgcn_mfma_f32_16x16x32_bf16(wx1[i], xv[i][0], a10, 0, 0, 0);
            a11 = __builtin_amdgcn_mfma_f32_16x16x32_bf16(wx1[i], xv[i][1], a11, 0, 0, 0);
        }

        // ---- h(t-1): per-wave sentinel poll on own 16 KB K-chunk.
        //      The attempt that passes IS the data load. ----
        const unsigned short* rb = ring + (size_t)slot * 32768;
        short8 hv[8][2];
        {
            const unsigned short* hp0 = rb + (size_t)(v * 8 * 128 + lane) * 8;
            for (;;) {
#pragma unroll
                for (int i = 0; i < 8; ++i) {
                    const unsigned short* hp = hp0 + (size_t)i * 1024;
                    hv[i][0] = coh_load16(hp);
                    hv[i][1] = coh_load16(hp + 512);
                }
                waitcnt_vm0();
                int ok = 1;
#pragma unroll
                for (int i = 0; i < 8; ++i)
#pragma unroll
                    for (int u = 0; u < 2; ++u) {
                        intx4 q = __builtin_bit_cast(intx4, hv[i][u]);
                        ok &= (q.x != -1) & (q.y != -1) & (q.z != -1) & (q.w != -1);
                    }
                if (__all(ok)) break;
                __builtin_amdgcn_s_sleep(1);
            }
        }

        // ---- h-part MFMAs (pure register chain) ----
#pragma unroll
        for (int i = 0; i < 8; ++i) {
            a00 = __builtin_amdgcn_mfma_f32_16x16x32_bf16(wh0[i], hv[i][0], a00, 0, 0, 0);
            a01 = __builtin_amdgcn_mfma_f32_16x16x32_bf16(wh0[i], hv[i][1], a01, 0, 0, 0);
            a10 = __builtin_amdgcn_mfma_f32_16x16x32_bf16(wh1[i], hv[i][0], a10, 0, 0, 0);
            a11 = __builtin_amdgcn_mfma_f32_16x16x32_bf16(wh1[i], hv[i][1], a11, 0, 0, 0);
        }

        // ---- cross-wave K reduction via LDS (swizzled) ----
        {
            int n = lane & 15, q = lane >> 4;
#pragma unroll
            for (int r = 0; r < 4; ++r) {
                int row = q * 4 + r;
                part[(v * 4 + 0) * 256 + PSWZ(row, n)] = a00[r];
                part[(v * 4 + 1) * 256 + PSWZ(row, n)] = a01[r];
                part[(v * 4 + 2) * 256 + PSWZ(row, n)] = a10[r];
                part[(v * 4 + 3) * 256 + PSWZ(row, n)] = a11[r];
            }
        }
        __syncthreads();
        // ---- retire slot of h(t-2): all 4 waves passed their polls of
        //      h(t-1) ==> every WG published h(t-1) ==> every WG is done
        //      re-reading h(t-2). Re-sentinel our own 512 B region.
        //      (wave 3, to keep wave 0's publish path clean) ----
        if (tid >= 192 && tid < 224) {
            int s32 = tid - 192;
            unsigned short* sp = ring + (size_t)((slot + RING - 1) & (RING - 1)) * 32768;
            int kb2   = w >> 2;
            int lane2 = ((w & 3) << 4) | (s32 & 15);
            intx4 ff = {-1, -1, -1, -1};
            coh_store16(sp + (size_t)((kb2 * 2 + (s32 >> 4)) * 64 + lane2) * 8, ff);
        }
        {
            int m = tid >> 4, n = tid & 15;
#pragma unroll
            for (int mt = 0; mt < 2; ++mt)
#pragma unroll
                for (int nb = 0; nb < 2; ++nb) {
                    int c = mt * 2 + nb;
                    float g = part[(0 * 4 + c) * 256 + PSWZ(m, n)]
                            + part[(1 * 4 + c) * 256 + PSWZ(m, n)]
                            + part[(2 * 4 + c) * 256 + PSWZ(m, n)]
                            + part[(3 * 4 + c) * 256 + PSWZ(m, n)];
                    gates[GSWZ(mt * 16 + m, nb * 16 + n)] = g + bias_s[mt * 16 + m];
                }
        }
        __syncthreads();

        // ---- gate nonlinearities + c/h update (one (hd,bb) per thread) ----
        float hval;
        {
            int r3 = hd & 3, mt = hd >> 2;
            float gi = gates[GSWZ(mt * 16 +  0 + r3, bb)];
            float gf = gates[GSWZ(mt * 16 +  4 + r3, bb)];
            float gg = gates[GSWZ(mt * 16 +  8 + r3, bb)];
            float go = gates[GSWZ(mt * 16 + 12 + r3, bb)];
            float i_ = fast_sigmoid(gi);
            float f_ = fast_sigmoid(gf);
            float g_ = fast_tanh(gg);
            float o_ = fast_sigmoid(go);
            creg = f_ * creg + i_ * g_;
            hval = o_ * fast_tanh(creg);
            ((unsigned short*)&hstage4[bb])[hd] = f2bf(hval);
        }
        __syncthreads();

        // ---- publish h(t): 32x16B coherent stores. No drain, no flag —
        //      consumers detect arrival via the sentinel check. ----
        int slot_out = (slot + 1) & (RING - 1);
        if (tid < 32) {
            unsigned short* hn = ring + (size_t)slot_out * 32768;
            int kb2   = w >> 2;
            int lane2 = ((w & 3) << 4) | (tid & 15);
            coh_store16(hn + (size_t)((kb2 * 2 + (tid >> 4)) * 64 + lane2) * 8,
                        hstage4[tid]);
        }
        // hs history store (not on the critical path)
        hs[((size_t)t * BATCH + bb) * HDIM + j] = hval;
        slot = slot_out;
    }
    cbuf[bb * HDIM + j] = creg;
}

// ---------------------------------------------------------------------------
// Adapter (x + up(relu(down(x)))) + LayerNorm. 8 rows per WG (2048 WGs):
// Adw/Auw streamed once per WG (L2 traffic /8), full-K per-thread dots.
// ---------------------------------------------------------------------------
__global__ void __launch_bounds__(256) adapter_ln(
    const float* __restrict__ xin,
    const float* __restrict__ Adw, const float* __restrict__ Adb,
    const float* __restrict__ Auw, const float* __restrict__ Aub,
    const float* __restrict__ lng, const float* __restrict__ lnb,
    float* __restrict__ outf, unsigned short* __restrict__ xfout)
{
    __shared__ float xs[AROWS * 1024];     // 32 KB
    __shared__ float dbuf[AROWS * 64];     // 2 KB
    __shared__ float red2[AROWS * 32 * 2]; // 2 KB
    __shared__ float mv[AROWS * 2];
    const int tid = threadIdx.x;
    const int r0  = blockIdx.x * AROWS;

    // stage 8 rows (coalesced float4)
    {
        const float4* src4 = (const float4*)(xin + (size_t)r0 * HDIM);
        float4* xs4 = (float4*)xs;
        for (int i = tid; i < AROWS * 256; i += 256) xs4[i] = src4[i];
    }
    __syncthreads();

    const int row = tid >> 5;   // 0..7
    const int sg  = tid & 31;

    // ---- down-proj: thread computes d[row][2 a's] over full K ----
    {
        const float4* w0 = (const float4*)Adw + (size_t)(sg * 2) * 256;
        const float4* w1 = w0 + 256;
        const float4* xr = (const float4*)xs + row * 256;
        float acc0 = 0.f, acc1 = 0.f;
#pragma unroll 4
        for (int k = 0; k < 256; ++k) {
            float4 xv = xr[k];
            float4 wa = w0[k], wb = w1[k];
            acc0 += wa.x*xv.x + wa.y*xv.y + wa.z*xv.z + wa.w*xv.w;
            acc1 += wb.x*xv.x + wb.y*xv.y + wb.z*xv.z + wb.w*xv.w;
        }
        acc0 += Adb[sg * 2];
        acc1 += Adb[sg * 2 + 1];
        dbuf[row * 64 + sg * 2]     = acc0 > 0.f ? acc0 : 0.f;
        dbuf[row * 64 + sg * 2 + 1] = acc1 > 0.f ? acc1 : 0.f;
    }
    __syncthreads();

    // ---- up-proj: thread owns 32 consecutive j for its row ----
    float4 dr[16];
    {
        const float4* dv = (const float4*)(dbuf + row * 64);
#pragma unroll
        for (int q = 0; q < 16; ++q) dr[q] = dv[q];
    }
    float y[32]; float s1 = 0.f, s2 = 0.f;
#pragma unroll 4
    for (int jj = 0; jj < 32; ++jj) {
        int jidx = sg * 32 + jj;
        const float4* urow = (const float4*)(Auw + (size_t)jidx * DA_DIM);
        float acc = xs[row * 1024 + jidx] + Aub[jidx];
#pragma unroll
        for (int q = 0; q < 16; ++q) {
            float4 uv = urow[q];
            acc += uv.x*dr[q].x + uv.y*dr[q].y + uv.z*dr[q].z + uv.w*dr[q].w;
        }
        y[jj] = acc; s1 += acc; s2 += acc * acc;
    }
    red2[(row * 32 + sg) * 2]     = s1;
    red2[(row * 32 + sg) * 2 + 1] = s2;
    __syncthreads();
    if (sg == 0) {
        float t1 = 0.f, t2 = 0.f;
        for (int q = 0; q < 32; ++q) {
            t1 += red2[(row * 32 + q) * 2];
            t2 += red2[(row * 32 + q) * 2 + 1];
        }
        float mean = t1 * (1.f / 1024.f);
        float var  = t2 * (1.f / 1024.f) - mean * mean;
        mv[row * 2]     = mean;
        mv[row * 2 + 1] = rsqrtf(var + EPS_LN);
    }
    __syncthreads();
    const float mean = mv[row * 2], rstd = mv[row * 2 + 1];
    const int rg = r0 + row;
    // normalize
#pragma unroll
    for (int jj = 0; jj < 32; ++jj) {
        int jidx = sg * 32 + jj;
        y[jj] = (y[jj] - mean) * rstd * lng[jidx] + lnb[jidx];
    }
    if (outf) {
        float4* o4 = (float4*)(outf + (size_t)rg * HDIM + sg * 32);
#pragma unroll
        for (int q = 0; q < 8; ++q) {
            float4 ov = { y[q*4], y[q*4+1], y[q*4+2], y[q*4+3] };
            o4[q] = ov;
        }
    }
    if (xfout) {
        int t = rg >> 5, b = rg & 31;
        int nb = b >> 4;
        unsigned short* base = xfout + (size_t)t * 32768;
#pragma unroll
        for (int g = 0; g < 4; ++g) {
            int lane2 = (g << 4) | (b & 15);
            unsigned short tmp[8];
#pragma unroll
            for (int e = 0; e < 8; ++e) tmp[e] = f2bf(y[g * 8 + e]);
            *(short8*)(base + (size_t)((sg * 2 + nb) * 64 + lane2) * 8) = *(short8*)tmp;
        }
    }
}

extern "C" void kernel_launch(void* const* d_in, const int* in_sizes, int n_in,
                              void* d_out, int out_size, void* d_ws, size_t ws_size,
                              hipStream_t stream)
{
    const float* x   = (const float*)d_in[0];
    const float* Wih = (const float*)d_in[1];
    const float* Whh = (const float*)d_in[2];
    const float* bih = (const float*)d_in[3];
    const float* bhh = (const float*)d_in[4];
    const float* Adw = (const float*)d_in[5];
    const float* Adb = (const float*)d_in[6];
    const float* Auw = (const float*)d_in[7];
    const float* Aub = (const float*)d_in[8];
    const float* lng = (const float*)d_in[9];
    const float* lnb = (const float*)d_in[10];
    float* out = (float*)d_out;

    // workspace carve (~52 MB)
    char* ws = (char*)d_ws;
    unsigned short* wfb  = (unsigned short*)ws; ws += (size_t)GATE4 * 2048 * 2;      // 16.78 MB
    unsigned short* xfb  = (unsigned short*)ws; ws += (size_t)T_STEPS * 32768 * 2;   // 33.55 MB
    unsigned short* ring = (unsigned short*)ws; ws += (size_t)RING * 32768 * 2;      // 1 MB
    float*    cbuf  = (float*)ws;    ws += (size_t)BATCH * HDIM * 4;                 // 128 KB
    float* hs = out;   // alias hs onto d_out x-region (adapter is in-place safe)

    hipMemsetAsync(cbuf, 0, (size_t)BATCH * HDIM * 4, stream);
    // slot 0 = h0 = zeros (valid data); slots 1..15 = 0xFF sentinel
    hipMemsetAsync(ring, 0, 65536, stream);
    hipMemsetAsync((char*)ring + 65536, 0xFF, (size_t)(RING - 1) * 65536, stream);

    prep_xfrag<<<8192, 256, 0, stream>>>(x, xfb);

    for (int l = 0; l < 2; ++l) {
        prep_wfrag<<<4096, 256, 0, stream>>>(Wih + (size_t)l * GATE4 * HDIM,
                                             Whh + (size_t)l * GATE4 * HDIM, wfb);
        // global step g = l*512 + t; slot_in = g & 15; 512 % 16 == 0 so slot0 = 0
        // for both layers and the sentinel protocol is continuous across layers.
        lstm_persistent<<<PWG, 256, 0, stream>>>(xfb, wfb, ring,
                                                 bih + (size_t)l * GATE4,
                                                 bhh + (size_t)l * GATE4,
                                                 cbuf, hs, 0);

        const float* adw = Adw + (size_t)l * DA_DIM * HDIM;
        const float* adb = Adb + (size_t)l * DA_DIM;
        const float* auw = Auw + (size_t)l * HDIM * DA_DIM;
        const float* aub = Aub + (size_t)l * HDIM;
        const float* lg  = lng + (size_t)l * HDIM;
        const float* lb  = lnb + (size_t)l * HDIM;
        if (l == 0) {
            adapter_ln<<<T_STEPS * BATCH / AROWS, 256, 0, stream>>>(
                hs, adw, adb, auw, aub, lg, lb, nullptr, xfb);
        } else {
            hipMemcpyAsync(out + 16777216, hs + (size_t)511 * BATCH * HDIM,
                           (size_t)BATCH * HDIM * 4, hipMemcpyDeviceToDevice, stream);
            hipMemcpyAsync(out + 16777216 + 32768, cbuf,
                           (size_t)BATCH * HDIM * 4, hipMemcpyDeviceToDevice, stream);
            adapter_ln<<<T_STEPS * BATCH / AROWS, 256, 0, stream>>>(
                hs, adw, adb, auw, aub, lg, lb, out, nullptr);
        }
    }
}